// Round 2
// baseline (505.948 us; speedup 1.0000x reference)
//
#include <hip/hip_runtime.h>
#include <hip/hip_bf16.h>

// Transformer block: B=4, S=2048, D=1024, H=4096, fp32 in/out, bf16 MFMA compute.
// Workspace arena (needs >= 152 MB):
//   0MB WqT | 2 WkT | 4 WvT | 6 WoT | 8 W1T(8MB) | 16 W2T(8MB) | 24 xn(16MB)
//   40 q/ao(16MB) | 56 k(16MB) | 72 vT(16MB) | 88 attn_bf16(32MB) | 120 x2 f32(32MB)
//   h(bf16, 64MB) reuses [56..120) after attention is done.

typedef __bf16 bf16_t;
typedef __bf16 bf16x8 __attribute__((ext_vector_type(8)));
typedef float  f32x4  __attribute__((ext_vector_type(4)));

#define EPI_BF16_BIAS      0
#define EPI_BF16T_BIAS     1
#define EPI_F32_SCALE      2
#define EPI_BF16           3
#define EPI_F32_BIAS_RES   4
#define EPI_BF16_RELU_BIAS 5

// C = A[M][K] * B^T where B is stored row-major [N][K] (both bf16), fp32 acc.
// 128x128 tile, 4 waves (2x2), each wave 64x64 = 4x4 mfma_f32_16x16x32_bf16.
template<int EPI>
__global__ __launch_bounds__(256, 2)
void gemm_bt(const bf16_t* __restrict__ A, const bf16_t* __restrict__ B,
             float* __restrict__ Cf, bf16_t* __restrict__ Cb,
             const float* __restrict__ bias, const float* __restrict__ resid,
             int M, int N, int K,
             long sAb, long sBb, long sCb, float scale)
{
  __shared__ __align__(16) bf16_t sA[128 * 32];
  __shared__ __align__(16) bf16_t sB[128 * 32];
  const int tid = threadIdx.x;
  const int bz  = blockIdx.z;
  const bf16_t* Ab = A + (long)bz * sAb;
  const bf16_t* Bb = B + (long)bz * sBb;
  const int m0 = blockIdx.y * 128, n0 = blockIdx.x * 128;
  const int lane = tid & 63;
  const int wm = ((tid >> 7) & 1) * 64;   // wave row (2x2 wave grid)
  const int wn = ((tid >> 6) & 1) * 64;   // wave col
  f32x4 acc[4][4] = {};
  const int lr = tid >> 2;          // 0..63 staging row
  const int lc = (tid & 3) * 8;     // 0,8,16,24 staging col (8 bf16 = 16B)
  const int kk = (lane >> 4) * 8;   // frag k-offset
  const int rA = wm + (lane & 15);
  const int rB = wn + (lane & 15);

  for (int k0 = 0; k0 < K; k0 += 32) {
    *(int4*)&sA[lr * 32 + lc]        = *(const int4*)(Ab + (long)(m0 + lr) * K      + k0 + lc);
    *(int4*)&sA[(lr + 64) * 32 + lc] = *(const int4*)(Ab + (long)(m0 + lr + 64) * K + k0 + lc);
    *(int4*)&sB[lr * 32 + lc]        = *(const int4*)(Bb + (long)(n0 + lr) * K      + k0 + lc);
    *(int4*)&sB[(lr + 64) * 32 + lc] = *(const int4*)(Bb + (long)(n0 + lr + 64) * K + k0 + lc);
    __syncthreads();
    bf16x8 af[4], bfv[4];
#pragma unroll
    for (int i = 0; i < 4; ++i) {
      af[i]  = *(const bf16x8*)&sA[(rA + i * 16) * 32 + kk];
      bfv[i] = *(const bf16x8*)&sB[(rB + i * 16) * 32 + kk];
    }
#pragma unroll
    for (int mi = 0; mi < 4; ++mi)
#pragma unroll
      for (int ni = 0; ni < 4; ++ni)
        acc[mi][ni] = __builtin_amdgcn_mfma_f32_16x16x32_bf16(af[mi], bfv[ni], acc[mi][ni], 0, 0, 0);
    __syncthreads();
  }

  // C/D layout (verified m89/m91): col = lane&15, row = (lane>>4)*4 + reg
  const int colB = n0 + wn + (lane & 15);
  const int rowB = m0 + wm + ((lane >> 4) << 2);
#pragma unroll
  for (int mi = 0; mi < 4; ++mi) {
#pragma unroll
    for (int ni = 0; ni < 4; ++ni) {
      const int col = colB + ni * 16;
#pragma unroll
      for (int j = 0; j < 4; ++j) {
        const int row = rowB + mi * 16 + j;
        const float v = acc[mi][ni][j];
        if constexpr (EPI == EPI_F32_SCALE) {
          Cf[sCb * bz + (long)row * N + col] = v * scale;
        } else if constexpr (EPI == EPI_BF16_BIAS) {
          Cb[(long)row * N + col] = (bf16_t)(v + bias[col]);
        } else if constexpr (EPI == EPI_BF16T_BIAS) {
          // row = b*2048 + t ; store vT[b][col][t]
          const int b = row >> 11, t = row & 2047;
          Cb[sCb * b + (long)col * 2048 + t] = (bf16_t)(v + bias[col]);
        } else if constexpr (EPI == EPI_BF16) {
          Cb[sCb * bz + (long)row * N + col] = (bf16_t)v;
        } else if constexpr (EPI == EPI_F32_BIAS_RES) {
          Cf[(long)row * N + col] = v + bias[col] + resid[(long)row * N + col];
        } else { // EPI_BF16_RELU_BIAS
          const float u = v + bias[col];
          Cb[(long)row * N + col] = (bf16_t)(u > 0.f ? u : 0.f);
        }
      }
    }
  }
}

// LayerNorm over D=1024, one block (256 thr) per row, out = bf16.
__global__ __launch_bounds__(256)
void ln_kernel(const float* __restrict__ x, const float* __restrict__ g,
               const float* __restrict__ be, bf16_t* __restrict__ out)
{
  const long row = blockIdx.x;
  const float4 v = *(const float4*)(x + row * 1024 + threadIdx.x * 4);
  float s  = v.x + v.y + v.z + v.w;
  float s2 = v.x * v.x + v.y * v.y + v.z * v.z + v.w * v.w;
  __shared__ float red[10];
  const int lane = threadIdx.x & 63, w = threadIdx.x >> 6;
#pragma unroll
  for (int off = 32; off; off >>= 1) {
    s  += __shfl_down(s, off);
    s2 += __shfl_down(s2, off);
  }
  if (lane == 0) { red[w] = s; red[4 + w] = s2; }
  __syncthreads();
  if (threadIdx.x == 0) {
    const float ts = red[0] + red[1] + red[2] + red[3];
    const float t2 = red[4] + red[5] + red[6] + red[7];
    const float mu = ts * (1.f / 1024.f);
    const float var = t2 * (1.f / 1024.f) - mu * mu;
    red[8] = mu;
    red[9] = rsqrtf(var + 1e-5f);
  }
  __syncthreads();
  const float mu = red[8], rinv = red[9];
  const int c = threadIdx.x * 4;
  const float4 gv = *(const float4*)(g + c);
  const float4 bv = *(const float4*)(be + c);
  bf16_t* o = out + row * 1024 + c;
  o[0] = (bf16_t)((v.x - mu) * rinv * gv.x + bv.x);
  o[1] = (bf16_t)((v.y - mu) * rinv * gv.y + bv.y);
  o[2] = (bf16_t)((v.z - mu) * rinv * gv.z + bv.z);
  o[3] = (bf16_t)((v.w - mu) * rinv * gv.w + bv.w);
}

// Row softmax over S=2048, in-place fp32 + bf16 copy. One block per row.
__global__ __launch_bounds__(256)
void softmax_kernel(float* __restrict__ sc, bf16_t* __restrict__ ab)
{
  const long row = blockIdx.x;
  float* sr = sc + row * 2048;
  const int t0 = threadIdx.x * 8;
  const float4 a = *(const float4*)(sr + t0);
  const float4 b = *(const float4*)(sr + t0 + 4);
  float mx = fmaxf(fmaxf(fmaxf(a.x, a.y), fmaxf(a.z, a.w)),
                   fmaxf(fmaxf(b.x, b.y), fmaxf(b.z, b.w)));
  __shared__ float red[4];
  __shared__ float bc[2];
  const int lane = threadIdx.x & 63, w = threadIdx.x >> 6;
#pragma unroll
  for (int off = 32; off; off >>= 1) mx = fmaxf(mx, __shfl_down(mx, off));
  if (lane == 0) red[w] = mx;
  __syncthreads();
  if (threadIdx.x == 0) bc[0] = fmaxf(fmaxf(red[0], red[1]), fmaxf(red[2], red[3]));
  __syncthreads();
  const float m = bc[0];
  float e[8];
  e[0] = __expf(a.x - m); e[1] = __expf(a.y - m); e[2] = __expf(a.z - m); e[3] = __expf(a.w - m);
  e[4] = __expf(b.x - m); e[5] = __expf(b.y - m); e[6] = __expf(b.z - m); e[7] = __expf(b.w - m);
  float s = e[0] + e[1] + e[2] + e[3] + e[4] + e[5] + e[6] + e[7];
#pragma unroll
  for (int off = 32; off; off >>= 1) s += __shfl_down(s, off);
  __syncthreads();  // all done reading red/bc from max phase
  if (lane == 0) red[w] = s;
  __syncthreads();
  if (threadIdx.x == 0) bc[1] = 1.f / (red[0] + red[1] + red[2] + red[3]);
  __syncthreads();
  const float inv = bc[1];
  float4 oa, ob;
  oa.x = e[0] * inv; oa.y = e[1] * inv; oa.z = e[2] * inv; oa.w = e[3] * inv;
  ob.x = e[4] * inv; ob.y = e[5] * inv; ob.z = e[6] * inv; ob.w = e[7] * inv;
  *(float4*)(sr + t0)     = oa;
  *(float4*)(sr + t0 + 4) = ob;
  bf16x8 o8;
  o8[0] = (bf16_t)oa.x; o8[1] = (bf16_t)oa.y; o8[2] = (bf16_t)oa.z; o8[3] = (bf16_t)oa.w;
  o8[4] = (bf16_t)ob.x; o8[5] = (bf16_t)ob.y; o8[6] = (bf16_t)ob.z; o8[7] = (bf16_t)ob.w;
  *(bf16x8*)(ab + row * 2048 + t0) = o8;
}

// WT[n][k] = (bf16)W[k][n]; W is [R][C] fp32. 32x32 LDS tile, 256 threads.
__global__ __launch_bounds__(256)
void transpose_cvt(const float* __restrict__ W, bf16_t* __restrict__ WT, int R, int C)
{
  __shared__ float t[32][33];
  const int c0 = blockIdx.x * 32, r0 = blockIdx.y * 32;
  const int tx = threadIdx.x & 31, ty = threadIdx.x >> 5;  // 32 x 8
#pragma unroll
  for (int i = 0; i < 32; i += 8)
    t[ty + i][tx] = W[(long)(r0 + ty + i) * C + c0 + tx];
  __syncthreads();
#pragma unroll
  for (int i = 0; i < 32; i += 8)
    WT[(long)(c0 + ty + i) * R + r0 + tx] = (bf16_t)t[tx][ty + i];
}

extern "C" void kernel_launch(void* const* d_in, const int* in_sizes, int n_in,
                              void* d_out, int out_size, void* d_ws, size_t ws_size,
                              hipStream_t stream)
{
  const float* x   = (const float*)d_in[0];
  const float* Wq  = (const float*)d_in[1];
  const float* bq  = (const float*)d_in[2];
  const float* Wk  = (const float*)d_in[3];
  const float* bk  = (const float*)d_in[4];
  const float* Wv  = (const float*)d_in[5];
  const float* bv  = (const float*)d_in[6];
  const float* Wo  = (const float*)d_in[7];
  const float* bo  = (const float*)d_in[8];
  const float* g1  = (const float*)d_in[9];
  const float* be1 = (const float*)d_in[10];
  const float* g2  = (const float*)d_in[11];
  const float* be2 = (const float*)d_in[12];
  const float* W1  = (const float*)d_in[13];
  const float* b1  = (const float*)d_in[14];
  const float* W2  = (const float*)d_in[15];
  const float* b2  = (const float*)d_in[16];

  float* out   = (float*)d_out;
  float* attnF = out + 8192L * 1024;   // [4][2048][2048] fp32 region

  char* ws = (char*)d_ws;
  const size_t MB = 1024 * 1024;
  bf16_t* WqT = (bf16_t*)(ws + 0 * MB);
  bf16_t* WkT = (bf16_t*)(ws + 2 * MB);
  bf16_t* WvT = (bf16_t*)(ws + 4 * MB);
  bf16_t* WoT = (bf16_t*)(ws + 6 * MB);
  bf16_t* W1T = (bf16_t*)(ws + 8 * MB);
  bf16_t* W2T = (bf16_t*)(ws + 16 * MB);
  bf16_t* xn  = (bf16_t*)(ws + 24 * MB);
  bf16_t* qB  = (bf16_t*)(ws + 40 * MB);  // q, later reused for attn_out (ao)
  bf16_t* kB  = (bf16_t*)(ws + 56 * MB);
  bf16_t* vT  = (bf16_t*)(ws + 72 * MB);  // [4][1024][2048]
  bf16_t* atB = (bf16_t*)(ws + 88 * MB);  // attn bf16 [4][2048][2048]
  float*  x2  = (float* )(ws + 120 * MB); // residual after attention, fp32
  bf16_t* hB  = (bf16_t*)(ws + 56 * MB);  // FFN hidden [8192][4096], reuses k/vT/attn

  // --- weight transpose + bf16 convert ---
  transpose_cvt<<<dim3(32, 32),  256, 0, stream>>>(Wq, WqT, 1024, 1024);
  transpose_cvt<<<dim3(32, 32),  256, 0, stream>>>(Wk, WkT, 1024, 1024);
  transpose_cvt<<<dim3(32, 32),  256, 0, stream>>>(Wv, WvT, 1024, 1024);
  transpose_cvt<<<dim3(32, 32),  256, 0, stream>>>(Wo, WoT, 1024, 1024);
  transpose_cvt<<<dim3(128, 32), 256, 0, stream>>>(W1, W1T, 1024, 4096);
  transpose_cvt<<<dim3(32, 128), 256, 0, stream>>>(W2, W2T, 4096, 1024);

  // --- LN1 ---
  ln_kernel<<<8192, 256, 0, stream>>>(x, g1, be1, xn);

  // --- QKV projections ---
  gemm_bt<EPI_BF16_BIAS><<<dim3(8, 64, 1), 256, 0, stream>>>(
      xn, WqT, nullptr, qB, bq, nullptr, 8192, 1024, 1024, 0, 0, 0, 1.f);
  gemm_bt<EPI_BF16_BIAS><<<dim3(8, 64, 1), 256, 0, stream>>>(
      xn, WkT, nullptr, kB, bk, nullptr, 8192, 1024, 1024, 0, 0, 0, 1.f);
  gemm_bt<EPI_BF16T_BIAS><<<dim3(8, 64, 1), 256, 0, stream>>>(
      xn, WvT, nullptr, vT, bv, nullptr, 8192, 1024, 1024, 0, 0, 2048L * 1024, 1.f);

  // --- scores = q k^T / sqrt(D), per batch, fp32 into d_out attn region ---
  gemm_bt<EPI_F32_SCALE><<<dim3(16, 16, 4), 256, 0, stream>>>(
      qB, kB, attnF, nullptr, nullptr, nullptr, 2048, 2048, 1024,
      2048L * 1024, 2048L * 1024, 2048L * 2048, 0.03125f);

  // --- softmax in-place + bf16 copy ---
  softmax_kernel<<<8192, 256, 0, stream>>>(attnF, atB);

  // --- attn_out = attn @ v  (B operand = vT, per batch) -> ao (reuse qB) ---
  gemm_bt<EPI_BF16><<<dim3(8, 16, 4), 256, 0, stream>>>(
      atB, vT, nullptr, qB, nullptr, nullptr, 2048, 1024, 2048,
      2048L * 2048, 1024L * 2048, 2048L * 1024, 1.f);

  // --- x2 = x + ao @ Wo + bo ---
  gemm_bt<EPI_F32_BIAS_RES><<<dim3(8, 64, 1), 256, 0, stream>>>(
      qB, WoT, x2, nullptr, bo, x, 8192, 1024, 1024, 0, 0, 0, 1.f);

  // --- LN2 ---
  ln_kernel<<<8192, 256, 0, stream>>>(x2, g2, be2, xn);

  // --- FFN ---
  gemm_bt<EPI_BF16_RELU_BIAS><<<dim3(32, 64, 1), 256, 0, stream>>>(
      xn, W1T, nullptr, hB, b1, nullptr, 8192, 4096, 1024, 0, 0, 0, 1.f);
  gemm_bt<EPI_F32_BIAS_RES><<<dim3(8, 64, 1), 256, 0, stream>>>(
      hB, W2T, out, nullptr, b2, x2, 8192, 1024, 4096, 0, 0, 0, 1.f);
}